// Round 11
// baseline (507.735 us; speedup 1.0000x reference)
//
#include <hip/hip_runtime.h>
#include <hip/hip_bf16.h>

typedef short bf16x8 __attribute__((ext_vector_type(8)));
typedef short bf16x4 __attribute__((ext_vector_type(4)));
typedef float f32x4  __attribute__((ext_vector_type(4)));

static constexpr int Bb   = 128;
static constexpr int Cin  = 32;
static constexpr int Nn   = 325;
static constexpr int Tt   = 24;
static constexpr int Cout = 64;
static constexpr int NKS  = 11;    // K steps (352 = 11*32)
static constexpr int WP2  = 352;   // padded w rows per (e,ks) plane
static constexpr int NWTB = 11;    // w-tiles of 32
static constexpr int NTH  = 3;     // t-tiles of 8
static constexpr size_t XTB_ELEMS = (size_t)Bb * NKS * (Tt * Cin) * 32;
static constexpr size_t STP_ELEMS = (size_t)3 * NKS * WP2 * 32;
static constexpr size_t WB_ELEMS  = (size_t)Cout * 128;

__device__ __forceinline__ void gld16(const void* g, void* l) {
    __builtin_amdgcn_global_load_lds(
        (const __attribute__((address_space(1))) void*)g,
        (__attribute__((address_space(3))) void*)l, 16, 0, 0);
}
__device__ __forceinline__ short bfb(float f) {
    __hip_bfloat16 h = __float2bfloat16(f);
    return *reinterpret_cast<short*>(&h);
}

// ---------- P1: stpb[ep][ks][w(352)][vi] = sup[ep][v][w], no identity -----
__global__ void build_stp(const float* __restrict__ sup,
                          __hip_bfloat16* __restrict__ stpb) {
    int idx = blockIdx.x * 256 + threadIdx.x;
    int total = 3 * NKS * WP2 * 32;
    if (idx >= total) return;
    int ep = idx / (NKS * WP2 * 32);
    int r  = idx % (NKS * WP2 * 32);
    int ks = r / (WP2 * 32);
    int r2 = r % (WP2 * 32);
    int w  = r2 / 32;
    int vi = r2 % 32;
    int v  = ks * 32 + vi;
    float val = 0.f;
    if (v < Nn && w < Nn)
        val = sup[((size_t)ep * Nn + v) * Nn + w];
    stpb[idx] = __float2bfloat16(val);
}

// ---------- P1b: W fp32 -> bf16 [64][128] ---------------------------------
__global__ void build_wb(const float* __restrict__ W,
                         __hip_bfloat16* __restrict__ Wb) {
    int i = blockIdx.x * 256 + threadIdx.x;
    if (i < Cout * 128) Wb[i] = __float2bfloat16(W[i]);
}

// ---------- P2: x -> xTb[b][ks][ct=t*32+c][vi(32)]; XCD-affine: b/16 ------
__global__ void transpose_x(const float* __restrict__ x,
                            __hip_bfloat16* __restrict__ xTb) {
    __shared__ __hip_bfloat16 ls[Cin * 32 * 28];   // [c][vi][28] 57344 B
    int xcd = blockIdx.x & 7;
    int idx = blockIdx.x >> 3;        // [0,176): 16 b x 11 ks
    int b   = xcd * 16 + idx / NKS;
    int ks  = idx % NKS;
    int tid = threadIdx.x;
    for (int i = 0; i < 24; ++i) {
        int f4 = i * 256 + tid;
        int c  = f4 / 192;
        int rm = f4 % 192;
        int vi = rm / 6;
        int t0 = (rm % 6) * 4;
        int v  = ks * 32 + vi;
        float4 val = make_float4(0.f, 0.f, 0.f, 0.f);
        if (v < Nn)
            val = *(const float4*)(x + (((size_t)(b * Cin + c) * Nn + v) * Tt + t0));
        bf16x4 pk = { bfb(val.x), bfb(val.y), bfb(val.z), bfb(val.w) };
        *(bf16x4*)&ls[(c * 32 + vi) * 28 + t0] = pk;
    }
    __syncthreads();
    for (int j = 0; j < 12; ++j) {
        int o    = j * 256 + tid;
        int row  = o >> 2;
        int slot = o & 3;
        int t = row >> 5, c = row & 31;
        union { short us[8]; bf16x8 v8; } pk;
#pragma unroll
        for (int q = 0; q < 8; ++q) {
            __hip_bfloat16 h = ls[(c * 32 + slot * 8 + q) * 28 + t];
            pk.us[q] = *reinterpret_cast<short*>(&h);
        }
        *(bf16x8*)((char*)xTb + ((size_t)(b * NKS + ks) * 768 + row) * 64 + slot * 16) = pk.v8;
    }
}

// ---------- M: block=(b,wt32,th8); 512thr; af in LDS; identity synth ------
__global__ __launch_bounds__(512, 4) void graphconv_main(
    const __hip_bfloat16* __restrict__ xTb,
    const __hip_bfloat16* __restrict__ stpb,
    const __hip_bfloat16* __restrict__ Wb,
    const float* __restrict__ bias,
    float* __restrict__ out) {
    // union: Ss (S' slabs, 33*2048=67584B) then reused as Os (32*32*9*4=36864B)
    __shared__ alignas(16) char smem[33 * 2048];
    __hip_bfloat16* Ss = (__hip_bfloat16*)smem;
    float*          Os = (float*)smem;

    // bijective XCD swizzle: 4224 = 8 * 528; th innermost, wt next (b-L2 reuse)
    int bid = blockIdx.x;
    int lg  = (bid & 7) * 528 + (bid >> 3);
    int b   = lg / 33;
    int r   = lg % 33;
    int wt  = r / NTH;
    int th  = r % NTH;
    int w0  = wt * 32, t0 = th * 8, ct0 = th * 256;

    int tid = threadIdx.x, wid = tid >> 6, lane = tid & 63;
    int cl = lane & 15, kg = lane >> 4;

    const char* xbase = (const char*)xTb + (size_t)b * NKS * 768 * 64 +
                        (size_t)(ct0 + wid * 32 + cl) * 64 + kg * 16;

    // ---- stage all S' slabs once: 66 gld16, R5-verified swizzle pair -----
    {
        int srow  = lane >> 2;
        int sslot = ((lane & 3) ^ ((lane >> 3) & 3)) << 4;
        for (int q = wid; q < 66; q += 8) {
            int slab = q >> 1, half = q & 1;
            gld16((const char*)stpb + (size_t)slab * 22528 +
                      (size_t)(w0 + half * 16 + srow) * 64 + sslot,
                  (char*)smem + slab * 2048 + half * 1024 + lane * 16);
        }
    }

    // ---- xf prologue: ks = 0,1 ----
    bf16x8 xf[3][2];
#pragma unroll
    for (int s = 0; s < 2; ++s)
#pragma unroll
        for (int j = 0; j < 2; ++j)
            xf[s][j] = *(const bf16x8*)(xbase + (size_t)s * 49152 + j * 1024);

    // identity B-frags (synthesized, no loads): hot iff kg == wf*2 + (cl>>3)
    bf16x8 af0[2];
#pragma unroll
    for (int wf = 0; wf < 2; ++wf) {
        short hot = (kg == wf * 2 + (cl >> 3)) ? (short)0x3F80 : (short)0;
        int he = cl & 7;
        bf16x8 z = { 0, 0, 0, 0, 0, 0, 0, 0 };
#pragma unroll
        for (int i = 0; i < 8; ++i)
            if (he == i) z[i] = hot;
        af0[wf] = z;
    }

    __syncthreads();   // Ss resident

    const int asw = (kg ^ ((cl >> 1) & 3)) << 4;   // read-side slot swizzle
    bf16x8 af[2][3][2];
#pragma unroll
    for (int ep = 0; ep < 3; ++ep)
#pragma unroll
        for (int wf = 0; wf < 2; ++wf)
            af[0][ep][wf] = *(const bf16x8*)((const char*)Ss +
                (size_t)(ep * NKS) * 2048 + (wf * 16 + cl) * 64 + asw);

    // ---- GEMM1: 2-ahead xf (global), 1-ahead af (LDS); identity at ks==wt
    f32x4 acc1[3][2][2] = {};   // [ep][wf][j]
    f32x4 aid[2][2]     = {};   // identity H-slice [wf][j]
#pragma unroll
    for (int ks = 0; ks < NKS; ++ks) {
        const int cur3 = ks % 3, pf3 = (ks + 2) % 3;
        const int cur2 = ks & 1, nx2 = cur2 ^ 1;
        if (ks + 2 < NKS) {
#pragma unroll
            for (int j = 0; j < 2; ++j)
                xf[pf3][j] = *(const bf16x8*)(xbase + (size_t)(ks + 2) * 49152 + j * 1024);
        }
        if (ks + 1 < NKS) {
#pragma unroll
            for (int ep = 0; ep < 3; ++ep)
#pragma unroll
                for (int wf = 0; wf < 2; ++wf)
                    af[nx2][ep][wf] = *(const bf16x8*)((const char*)Ss +
                        (size_t)(ep * NKS + ks + 1) * 2048 + (wf * 16 + cl) * 64 + asw);
        }
        __builtin_amdgcn_s_setprio(1);
#pragma unroll
        for (int ep = 0; ep < 3; ++ep)
#pragma unroll
            for (int wf = 0; wf < 2; ++wf)
#pragma unroll
                for (int j = 0; j < 2; ++j)
                    acc1[ep][wf][j] = __builtin_amdgcn_mfma_f32_16x16x32_bf16(
                        xf[cur3][j], af[cur2][ep][wf], acc1[ep][wf][j], 0, 0, 0);
        if (ks == wt) {
#pragma unroll
            for (int wf = 0; wf < 2; ++wf)
#pragma unroll
                for (int j = 0; j < 2; ++j)
                    aid[wf][j] = __builtin_amdgcn_mfma_f32_16x16x32_bf16(
                        xf[cur3][j], af0[wf], aid[wf][j], 0, 0, 0);
        }
        __builtin_amdgcn_s_setprio(0);
    }

    // ---- GEMM2 from registers: kappa = es*2 + h; pb = (es==0?aid:acc1) ---
    // lane value: Y[w = w0+wf*16+cl][c = h*16+kg*4+r], t = t0+wid.
    f32x4 acc2[4][2] = {};
#pragma unroll
    for (int kappa = 0; kappa < 8; ++kappa) {
        const int es = kappa >> 1, h = kappa & 1;
        bf16x4 wfr[4];
#pragma unroll
        for (int mt = 0; mt < 4; ++mt)
            wfr[mt] = *(const bf16x4*)((const char*)Wb + (mt * 16 + cl) * 256 +
                                       kappa * 32 + kg * 8);
#pragma unroll
        for (int wf = 0; wf < 2; ++wf) {
            f32x4 y = (es == 0) ? aid[wf][h] : acc1[es - 1][wf][h];
            bf16x4 pb = { bfb(y[0]), bfb(y[1]), bfb(y[2]), bfb(y[3]) };
#pragma unroll
            for (int mt = 0; mt < 4; ++mt)
                acc2[mt][wf] = __builtin_amdgcn_mfma_f32_16x16x16bf16_1k(
                    wfr[mt], pb, acc2[mt][wf], 0, 0, 0);
        }
    }

    // ---- epilogue: Os overlays Ss; 2 passes of 32 o; full-line stores ----
    __syncthreads();   // all waves done reading Ss
#pragma unroll
    for (int p = 0; p < 2; ++p) {
        if (p) __syncthreads();
#pragma unroll
        for (int mh = 0; mh < 2; ++mh) {
            const int mt = p * 2 + mh;
#pragma unroll
            for (int wf = 0; wf < 2; ++wf)
#pragma unroll
                for (int r2_ = 0; r2_ < 4; ++r2_) {
                    int ol = mh * 16 + kg * 4 + r2_;
                    Os[(ol * 32 + wf * 16 + cl) * 9 + wid] = acc2[mt][wf][r2_];
                }
        }
        __syncthreads();
#pragma unroll
        for (int hh = 0; hh < 2; ++hh) {
            int pair = hh * 512 + tid;          // 1024 (o,w) pairs
            int ol = pair >> 5, w = pair & 31;
            int o  = p * 32 + ol;
            int wg = w0 + w;
            if (wg < Nn) {
                float bv = bias[o];
                float f[8];
#pragma unroll
                for (int q = 0; q < 8; ++q)
                    f[q] = Os[(ol * 32 + w) * 9 + q] + bv;
                float* op = out + ((size_t)(b * Cout + o) * Nn + wg) * Tt + t0;
                *(float4*)op       = make_float4(f[0], f[1], f[2], f[3]);
                *(float4*)(op + 4) = make_float4(f[4], f[5], f[6], f[7]);
            }
        }
    }
}

extern "C" void kernel_launch(void* const* d_in, const int* in_sizes, int n_in,
                              void* d_out, int out_size, void* d_ws, size_t ws_size,
                              hipStream_t stream) {
    const float* x    = (const float*)d_in[0];
    const float* sup  = (const float*)d_in[1];
    const float* W    = (const float*)d_in[2];
    const float* bias = (const float*)d_in[3];
    float* out = (float*)d_out;

    __hip_bfloat16* xTb  = (__hip_bfloat16*)d_ws;
    __hip_bfloat16* stpb = xTb + XTB_ELEMS;
    __hip_bfloat16* Wb   = stpb + STP_ELEMS;

    build_stp<<<(int)((STP_ELEMS + 255) / 256), 256, 0, stream>>>(sup, stpb);
    build_wb<<<(int)((WB_ELEMS + 255) / 256), 256, 0, stream>>>(W, Wb);
    transpose_x<<<Bb * NKS, 256, 0, stream>>>(x, xTb);
    graphconv_main<<<Bb * NWTB * NTH, 512, 0, stream>>>(xTb, stpb, Wb, bias, out);
}

// Round 12
// 441.142 us; speedup vs baseline: 1.1510x; 1.1510x over previous
//
#include <hip/hip_runtime.h>
#include <hip/hip_bf16.h>

typedef short bf16x8 __attribute__((ext_vector_type(8)));
typedef short bf16x4 __attribute__((ext_vector_type(4)));
typedef float f32x4  __attribute__((ext_vector_type(4)));
typedef float f32x16 __attribute__((ext_vector_type(16)));

static constexpr int Bb   = 128;
static constexpr int Cin  = 32;
static constexpr int Nn   = 325;
static constexpr int Tt   = 24;
static constexpr int Cout = 64;
static constexpr int NKS  = 11;    // K steps of 32 (352)
static constexpr int WP2  = 352;   // padded w rows per (e,ks) plane
static constexpr int NWTB = 11;    // w-tiles of 32
static constexpr size_t XTB_ELEMS = (size_t)Bb * NKS * (Tt * Cin) * 32;
static constexpr size_t STP_ELEMS = (size_t)3 * NKS * WP2 * 32;
static constexpr size_t WB_ELEMS  = (size_t)Cout * 128;

__device__ __forceinline__ short bfb(float f) {
    __hip_bfloat16 h = __float2bfloat16(f);
    return *reinterpret_cast<short*>(&h);
}

// ---------- P1: stpb[ep][ks][w(352)][vi] = sup[ep][v][w] ------------------
__global__ void build_stp(const float* __restrict__ sup,
                          __hip_bfloat16* __restrict__ stpb) {
    int idx = blockIdx.x * 256 + threadIdx.x;
    int total = 3 * NKS * WP2 * 32;
    if (idx >= total) return;
    int ep = idx / (NKS * WP2 * 32);
    int r  = idx % (NKS * WP2 * 32);
    int ks = r / (WP2 * 32);
    int r2 = r % (WP2 * 32);
    int w  = r2 / 32;
    int vi = r2 % 32;
    int v  = ks * 32 + vi;
    float val = 0.f;
    if (v < Nn && w < Nn)
        val = sup[((size_t)ep * Nn + v) * Nn + w];
    stpb[idx] = __float2bfloat16(val);
}

// ---------- P1b: W fp32 -> bf16 [64][128] ---------------------------------
__global__ void build_wb(const float* __restrict__ W,
                         __hip_bfloat16* __restrict__ Wb) {
    int i = blockIdx.x * 256 + threadIdx.x;
    if (i < Cout * 128) Wb[i] = __float2bfloat16(W[i]);
}

// ---------- P2: x -> xTb[b][ks][row = t*32 + pi(c)][vi(32)] ---------------
// pi(c) swaps bits 2,3 of c (involution) -> GEMM2 B-frags become direct
// register slices of GEMM1's 32x32 accumulator.
__global__ void transpose_x(const float* __restrict__ x,
                            __hip_bfloat16* __restrict__ xTb) {
    __shared__ __hip_bfloat16 ls[Cin * 32 * 28];   // [c][vi][28]
    int xcd = blockIdx.x & 7;
    int idx = blockIdx.x >> 3;        // [0,176): 16 b x 11 ks
    int b   = xcd * 16 + idx / NKS;
    int ks  = idx % NKS;
    int tid = threadIdx.x;
    for (int i = 0; i < 24; ++i) {
        int f4 = i * 256 + tid;
        int c  = f4 / 192;
        int rm = f4 % 192;
        int vi = rm / 6;
        int t0 = (rm % 6) * 4;
        int v  = ks * 32 + vi;
        float4 val = make_float4(0.f, 0.f, 0.f, 0.f);
        if (v < Nn)
            val = *(const float4*)(x + (((size_t)(b * Cin + c) * Nn + v) * Tt + t0));
        bf16x4 pk = { bfb(val.x), bfb(val.y), bfb(val.z), bfb(val.w) };
        *(bf16x4*)&ls[(c * 32 + vi) * 28 + t0] = pk;
    }
    __syncthreads();
    for (int j = 0; j < 12; ++j) {
        int o    = j * 256 + tid;
        int row  = o >> 2;
        int slot = o & 3;
        int t = row >> 5, m = row & 31;
        int c = (m & 0x13) | ((m & 4) << 1) | ((m & 8) >> 1);   // pi(m)
        union { short us[8]; bf16x8 v8; } pk;
#pragma unroll
        for (int q = 0; q < 8; ++q) {
            __hip_bfloat16 h = ls[(c * 32 + slot * 8 + q) * 28 + t];
            pk.us[q] = *reinterpret_cast<short*>(&h);
        }
        *(bf16x8*)((char*)xTb + ((size_t)(b * NKS + ks) * 768 + row) * 64 + slot * 16) = pk.v8;
    }
}

// ---------- M: block=(b,wt32,th12); 12 waves, 1 t/wave; 32x32 MFMA --------
__global__ __launch_bounds__(768, 3) void graphconv_main(
    const __hip_bfloat16* __restrict__ xTb,
    const __hip_bfloat16* __restrict__ stpb,
    const __hip_bfloat16* __restrict__ Wb,
    const float* __restrict__ bias,
    float* __restrict__ out) {
    // Ss: 33 slabs x [32 w][72B] = 76032 B; overlaid by Os (32x32x13 f32)
    __shared__ alignas(16) char smem[33 * 2304];
    float* Os = (float*)smem;

    // bijective XCD swizzle: 2816 = 8 * 352
    int bid = blockIdx.x;
    int lg  = (bid & 7) * 352 + (bid >> 3);
    int b   = lg / 22;
    int r   = lg % 22;
    int wt  = r >> 1, th = r & 1;
    int w0  = wt * 32, t0 = th * 12;

    int tid = threadIdx.x, wid = tid >> 6, lane = tid & 63;
    int wl = lane & 31, h = lane >> 5;

    // ---- stage S' (3 planes x 11 ks, this w-tile) to LDS, 72B rows -------
    for (int f = tid; f < 33 * 128; f += 768) {
        int slab = f >> 7, wi = f & 127;
        int row = wi >> 2, slot = wi & 3;
        bf16x8 v = *(const bf16x8*)((const char*)stpb +
                       ((size_t)slab * WP2 + w0 + row) * 64 + slot * 16);
        *(bf16x8*)(smem + slab * 2304 + row * 72 + slot * 16) = v;
    }

    // ---- xf prologue (global, independent of LDS): ks=0 ----
    const char* xbase = (const char*)xTb + (size_t)b * NKS * 768 * 64 +
                        (size_t)((t0 + wid) * 32 + wl) * 64 + h * 16;
    bf16x8 xf[2][2];
#pragma unroll
    for (int sub = 0; sub < 2; ++sub)
        xf[0][sub] = *(const bf16x8*)(xbase + sub * 32);

    // identity A..B-frag synth: hot element j = wl&7, iff (wl>>3)==sub*2+h
    bf16x8 id[2];
#pragma unroll
    for (int sub = 0; sub < 2; ++sub) {
        short hot = ((wl >> 3) == sub * 2 + h) ? (short)0x3F80 : (short)0;
        bf16x8 z = { 0, 0, 0, 0, 0, 0, 0, 0 };
#pragma unroll
        for (int i = 0; i < 8; ++i)
            z[i] = (i == (wl & 7)) ? hot : (short)0;
        id[sub] = z;
    }

    __syncthreads();   // Ss resident

    // af LDS read helper offsets: slab*2304 + wl*72 + sub*32 + h*16
    const char* afb = smem + (size_t)wl * 72 + h * 16;

    bf16x8 afA[3], afB[3];
#pragma unroll
    for (int ep = 0; ep < 3; ++ep)
        afA[ep] = *(const bf16x8*)(afb + (ep * NKS) * 2304);

    f32x16 acc1[3] = {};
    f32x16 aid = {};

    for (int ks = 0; ks < NKS; ++ks) {
        const int cur = ks & 1;
        if (ks + 1 < NKS) {
#pragma unroll
            for (int sub = 0; sub < 2; ++sub)
                xf[cur ^ 1][sub] = *(const bf16x8*)(xbase + (size_t)(ks + 1) * 49152 + sub * 32);
        }
        // sub 0 (prefetch sub1 af)
#pragma unroll
        for (int ep = 0; ep < 3; ++ep)
            afB[ep] = *(const bf16x8*)(afb + (size_t)(ep * NKS + ks) * 2304 + 32);
        __builtin_amdgcn_s_setprio(1);
#pragma unroll
        for (int ep = 0; ep < 3; ++ep)
            acc1[ep] = __builtin_amdgcn_mfma_f32_32x32x16_bf16(
                xf[cur][0], afA[ep], acc1[ep], 0, 0, 0);
        if (ks == wt)
            aid = __builtin_amdgcn_mfma_f32_32x32x16_bf16(xf[cur][0], id[0], aid, 0, 0, 0);
        __builtin_amdgcn_s_setprio(0);
        // sub 1 (prefetch next-ks sub0 af)
        if (ks + 1 < NKS) {
#pragma unroll
            for (int ep = 0; ep < 3; ++ep)
                afA[ep] = *(const bf16x8*)(afb + (size_t)(ep * NKS + ks + 1) * 2304);
        }
        __builtin_amdgcn_s_setprio(1);
#pragma unroll
        for (int ep = 0; ep < 3; ++ep)
            acc1[ep] = __builtin_amdgcn_mfma_f32_32x32x16_bf16(
                xf[cur][1], afB[ep], acc1[ep], 0, 0, 0);
        if (ks == wt)
            aid = __builtin_amdgcn_mfma_f32_32x32x16_bf16(xf[cur][1], id[1], aid, 0, 0, 0);
        __builtin_amdgcn_s_setprio(0);
    }

    // ---- GEMM2: acc2[ot] += W-frag x pb; pb = reg-slice of acc1/aid ------
    f32x16 acc2[2] = {};
#pragma unroll
    for (int es = 0; es < 4; ++es) {
        f32x16 y = (es == 0) ? aid : (es == 1) ? acc1[0] : (es == 2) ? acc1[1] : acc1[2];
#pragma unroll
        for (int ch = 0; ch < 2; ++ch) {
            bf16x8 pb;
#pragma unroll
            for (int j = 0; j < 8; ++j)
                pb[j] = bfb(y[ch * 8 + j]);
#pragma unroll
            for (int ot = 0; ot < 2; ++ot) {
                bf16x8 wf = *(const bf16x8*)((const char*)Wb +
                    (ot * 32 + wl) * 256 + es * 64 + ch * 32 + h * 16);
                acc2[ot] = __builtin_amdgcn_mfma_f32_32x32x16_bf16(
                    wf, pb, acc2[ot], 0, 0, 0);
            }
        }
    }

    // ---- epilogue: 2 passes of 32 o; Os[o_loc][w][13-pad t]; 48B stores --
#pragma unroll
    for (int p = 0; p < 2; ++p) {
        __syncthreads();   // p0: af reads done; p1: pass-0 reads done
#pragma unroll
        for (int rg = 0; rg < 16; ++rg) {
            int o_loc = (rg & 3) + 8 * (rg >> 2) + 4 * h;
            Os[(o_loc * 32 + wl) * 13 + wid] = acc2[p][rg];
        }
        __syncthreads();
        for (int pair = tid; pair < 1024; pair += 768) {
            int ol = pair >> 5, w = pair & 31;
            int o  = p * 32 + ol;
            int wg = w0 + w;
            if (wg < Nn) {
                float bv = bias[o];
                float f[12];
#pragma unroll
                for (int q = 0; q < 12; ++q)
                    f[q] = Os[pair * 13 + q] + bv;
                float* op = out + ((size_t)(b * Cout + o) * Nn + wg) * Tt + t0;
#pragma unroll
                for (int q3 = 0; q3 < 3; ++q3)
                    *(float4*)(op + q3 * 4) = make_float4(
                        f[q3 * 4], f[q3 * 4 + 1], f[q3 * 4 + 2], f[q3 * 4 + 3]);
            }
        }
    }
}

extern "C" void kernel_launch(void* const* d_in, const int* in_sizes, int n_in,
                              void* d_out, int out_size, void* d_ws, size_t ws_size,
                              hipStream_t stream) {
    const float* x    = (const float*)d_in[0];
    const float* sup  = (const float*)d_in[1];
    const float* W    = (const float*)d_in[2];
    const float* bias = (const float*)d_in[3];
    float* out = (float*)d_out;

    __hip_bfloat16* xTb  = (__hip_bfloat16*)d_ws;
    __hip_bfloat16* stpb = xTb + XTB_ELEMS;
    __hip_bfloat16* Wb   = stpb + STP_ELEMS;

    build_stp<<<(int)((STP_ELEMS + 255) / 256), 256, 0, stream>>>(sup, stpb);
    build_wb<<<(int)((WB_ELEMS + 255) / 256), 256, 0, stream>>>(W, Wb);
    transpose_x<<<Bb * NKS, 256, 0, stream>>>(x, xTb);
    graphconv_main<<<Bb * NWTB * 2, 768, 0, stream>>>(xTb, stpb, Wb, bias, out);
}

// Round 13
// 437.941 us; speedup vs baseline: 1.1594x; 1.0073x over previous
//
#include <hip/hip_runtime.h>
#include <hip/hip_bf16.h>

typedef short bf16x8 __attribute__((ext_vector_type(8)));
typedef short bf16x4 __attribute__((ext_vector_type(4)));
typedef float f32x4  __attribute__((ext_vector_type(4)));

static constexpr int Bb   = 128;
static constexpr int Cin  = 32;
static constexpr int Nn   = 325;
static constexpr int Tt   = 24;
static constexpr int Cout = 64;
static constexpr int NKS  = 11;    // K steps of 32 (352)
static constexpr int WP2  = 352;   // padded w rows per (ep,ks) plane
static constexpr int NWT  = 21;    // w-tiles of 16
static constexpr size_t XTB_ELEMS = (size_t)Bb * NKS * (Tt * Cin) * 32;
static constexpr size_t STP_ELEMS = (size_t)3 * NKS * WP2 * 32;
static constexpr size_t WB_ELEMS  = (size_t)Cout * 128;

__device__ __forceinline__ void gld16(const void* g, void* l) {
    __builtin_amdgcn_global_load_lds(
        (const __attribute__((address_space(1))) void*)g,
        (__attribute__((address_space(3))) void*)l, 16, 0, 0);
}
__device__ __forceinline__ short bfb(float f) {
    __hip_bfloat16 h = __float2bfloat16(f);
    return *reinterpret_cast<short*>(&h);
}

// ---------- P1: stpb[ep][ks][w(352)][vi] = sup[ep][v][w] (no identity) ----
__global__ void build_stp(const float* __restrict__ sup,
                          __hip_bfloat16* __restrict__ stpb) {
    int idx = blockIdx.x * 256 + threadIdx.x;
    int total = 3 * NKS * WP2 * 32;
    if (idx >= total) return;
    int ep = idx / (NKS * WP2 * 32);
    int r  = idx % (NKS * WP2 * 32);
    int ks = r / (WP2 * 32);
    int r2 = r % (WP2 * 32);
    int w  = r2 / 32;
    int vi = r2 % 32;
    int v  = ks * 32 + vi;
    float val = 0.f;
    if (v < Nn && w < Nn)
        val = sup[((size_t)ep * Nn + v) * Nn + w];
    stpb[idx] = __float2bfloat16(val);
}

// ---------- P1b: W fp32 -> bf16 [64][128] ---------------------------------
__global__ void build_wb(const float* __restrict__ W,
                         __hip_bfloat16* __restrict__ Wb) {
    int i = blockIdx.x * 256 + threadIdx.x;
    if (i < Cout * 128) Wb[i] = __float2bfloat16(W[i]);
}

// ---------- P2: x -> xTb[b][ks][row=t*32+c][vi(32)] (R9 version, no pi) ---
__global__ void transpose_x(const float* __restrict__ x,
                            __hip_bfloat16* __restrict__ xTb) {
    __shared__ __hip_bfloat16 ls[Cin * 32 * 28];   // [c][vi][28]
    int xcd = blockIdx.x & 7;
    int idx = blockIdx.x >> 3;        // [0,176): 16 b x 11 ks
    int b   = xcd * 16 + idx / NKS;
    int ks  = idx % NKS;
    int tid = threadIdx.x;
    for (int i = 0; i < 24; ++i) {
        int f4 = i * 256 + tid;
        int c  = f4 / 192;
        int rm = f4 % 192;
        int vi = rm / 6;
        int t0 = (rm % 6) * 4;
        int v  = ks * 32 + vi;
        float4 val = make_float4(0.f, 0.f, 0.f, 0.f);
        if (v < Nn)
            val = *(const float4*)(x + (((size_t)(b * Cin + c) * Nn + v) * Tt + t0));
        bf16x4 pk = { bfb(val.x), bfb(val.y), bfb(val.z), bfb(val.w) };
        *(bf16x4*)&ls[(c * 32 + vi) * 28 + t0] = pk;
    }
    __syncthreads();
    for (int j = 0; j < 12; ++j) {
        int o    = j * 256 + tid;
        int row  = o >> 2;
        int slot = o & 3;
        int t = row >> 5, c = row & 31;
        union { short us[8]; bf16x8 v8; } pk;
#pragma unroll
        for (int q = 0; q < 8; ++q) {
            __hip_bfloat16 h = ls[(c * 32 + slot * 8 + q) * 28 + t];
            pk.us[q] = *reinterpret_cast<short*>(&h);
        }
        *(bf16x8*)((char*)xTb + ((size_t)(b * NKS + ks) * 768 + row) * 64 + slot * 16) = pk.v8;
    }
}

// ---------- M: 12 waves (1 t each); self-staged LDS X-ring, counted vmcnt -
__global__ __launch_bounds__(768, 3) void graphconv_main(
    const __hip_bfloat16* __restrict__ xTb,
    const __hip_bfloat16* __restrict__ stpb,
    const __hip_bfloat16* __restrict__ Wb,
    const float* __restrict__ bias,
    float* __restrict__ out) {
    // [Xring 2 x 24576][Ss 33 x 1024] = 82944 B; Os (53.5 KB) overlays front
    __shared__ alignas(16) char smem[2 * 24576 + 33 * 1024];
    char* Ss = smem + 2 * 24576;
    float* Os = (float*)smem;

    // bijective XCD swizzle: 5376 = 8 * 672; th innermost, wt next
    int bid = blockIdx.x;
    int lg  = (bid & 7) * 672 + (bid >> 3);
    int b   = lg / 42;
    int r   = lg % 42;
    int wt  = r >> 1, th = r & 1;
    int w0  = wt * 16, t0 = th * 12;

    int tid = threadIdx.x, wid = tid >> 6, lane = tid & 63;
    int cl = lane & 15, kg = lane >> 4;

    // staging lane constants (R5-verified swizzle pair)
    int srow  = lane >> 2;
    int sslot = ((lane & 3) ^ ((lane >> 3) & 3)) << 4;
    const int asw = (kg ^ ((cl >> 1) & 3)) << 4;   // read-side

    const char* xslab = (const char*)xTb + (size_t)b * NKS * 768 * 64;
    // wave's X rows for K-step ks, chunk q: row (t0+wid)*32 + q*16 + srow
    const char* xsrc = xslab + (size_t)((t0 + wid) * 32 + srow) * 64 + sslot;
    char* xdst = smem + wid * 2048 + lane * 16;

    // ---- prologue: S' (3/wave), then X buf0, buf1 ----
    if (wid < 11) {
#pragma unroll
        for (int q = 0; q < 3; ++q) {
            int i = wid * 3 + q;   // slab = ep*11 + ks
            gld16(stpb == nullptr ? nullptr :
                  (const char*)stpb + ((size_t)i * WP2 + w0 + srow) * 64 + sslot,
                  Ss + i * 1024 + lane * 16);
        }
    }
#pragma unroll
    for (int s = 0; s < 2; ++s)
#pragma unroll
        for (int q = 0; q < 2; ++q)
            gld16(xsrc + (size_t)s * 49152 + q * 1024,
                  xdst + s * 24576 + q * 1024);

    // identity B-frag: B[k][cl]=1 at ks==wt>>1, k=16*(wt&1)+cl
    bf16x8 idf;
    {
        short hot = (kg == 2 * (wt & 1) + (cl >> 3)) ? (short)0x3F80 : (short)0;
        bf16x8 z = { 0, 0, 0, 0, 0, 0, 0, 0 };
#pragma unroll
        for (int i = 0; i < 8; ++i)
            z[i] = (i == (cl & 7)) ? hot : (short)0;
        idf = z;
    }

    asm volatile("s_waitcnt vmcnt(4)" ::: "memory");   // S' arrived (own)
    __syncthreads();                                   // S' visible to all
    __builtin_amdgcn_sched_barrier(0);

    // ---- K-loop: zero barriers; wave-private ring; counted vmcnt ----
    f32x4 acc1[3][2] = {};   // [ep][j]
    f32x4 aid[2]     = {};
    const int id_ks = wt >> 1;
#pragma unroll
    for (int ks = 0; ks < NKS; ++ks) {
        if (ks < 10) { asm volatile("s_waitcnt vmcnt(2)" ::: "memory"); }
        else         { asm volatile("s_waitcnt vmcnt(0)" ::: "memory"); }
        __builtin_amdgcn_sched_barrier(0);
        const int bsel = (ks & 1) * 24576;
        bf16x8 xf[2], af[3];
#pragma unroll
        for (int j = 0; j < 2; ++j)
            xf[j] = *(const bf16x8*)(smem + bsel + wid * 2048 + j * 1024 +
                                     cl * 64 + asw);
#pragma unroll
        for (int ep = 0; ep < 3; ++ep)
            af[ep] = *(const bf16x8*)(Ss + (ep * NKS + ks) * 1024 + cl * 64 + asw);
        __builtin_amdgcn_s_setprio(1);
#pragma unroll
        for (int ep = 0; ep < 3; ++ep)
#pragma unroll
            for (int j = 0; j < 2; ++j)
                acc1[ep][j] = __builtin_amdgcn_mfma_f32_16x16x32_bf16(
                    xf[j], af[ep], acc1[ep][j], 0, 0, 0);
        if (ks == id_ks) {
#pragma unroll
            for (int j = 0; j < 2; ++j)
                aid[j] = __builtin_amdgcn_mfma_f32_16x16x32_bf16(
                    xf[j], idf, aid[j], 0, 0, 0);
        }
        __builtin_amdgcn_s_setprio(0);
        if (ks + 2 < NKS) {   // restage own region (reads above are complete)
            asm volatile("s_waitcnt lgkmcnt(0)" ::: "memory");
            __builtin_amdgcn_sched_barrier(0);
#pragma unroll
            for (int q = 0; q < 2; ++q)
                gld16(xsrc + (size_t)(ks + 2) * 49152 + q * 1024,
                      xdst + bsel + q * 1024);
        }
    }

    // ---- GEMM2 from registers: kappa = es*2 + j; pb = reg-slice ----
    // lane holds Y[c = j*16 + kg*4 + r][w = w0+cl] for t = t0+wid.
    f32x4 acc2[4] = {};
#pragma unroll
    for (int kappa = 0; kappa < 8; ++kappa) {
        const int es = kappa >> 1, j = kappa & 1;
        f32x4 y = (es == 0) ? aid[j] : acc1[es - 1][j];
        bf16x4 pb = { bfb(y[0]), bfb(y[1]), bfb(y[2]), bfb(y[3]) };
#pragma unroll
        for (int mt = 0; mt < 4; ++mt) {
            bf16x4 wf = *(const bf16x4*)((const char*)Wb + (mt * 16 + cl) * 256 +
                                         kappa * 32 + kg * 8);
            acc2[mt] = __builtin_amdgcn_mfma_f32_16x16x16bf16_1k(
                wf, pb, acc2[mt], 0, 0, 0);
        }
    }

    // ---- epilogue: Os[o*209 + w*13 + t]; one pass; full 48B stores ----
    __syncthreads();   // everyone done with ring/Ss reads
#pragma unroll
    for (int mt = 0; mt < 4; ++mt)
#pragma unroll
        for (int r2_ = 0; r2_ < 4; ++r2_) {
            int o = mt * 16 + kg * 4 + r2_;
            Os[o * 209 + cl * 13 + wid] = acc2[mt][r2_];
        }
    __syncthreads();
    for (int pair = tid; pair < 1024; pair += 768) {
        int o = pair >> 4, w = pair & 15;
        int wg = w0 + w;
        if (wg < Nn) {
            float bv = bias[o];
            float f[12];
#pragma unroll
            for (int q = 0; q < 12; ++q)
                f[q] = Os[o * 209 + w * 13 + q] + bv;
            float* op = out + ((size_t)(b * Cout + o) * Nn + wg) * Tt + th * 12;
#pragma unroll
            for (int q3 = 0; q3 < 3; ++q3)
                *(float4*)(op + q3 * 4) = make_float4(
                    f[q3 * 4], f[q3 * 4 + 1], f[q3 * 4 + 2], f[q3 * 4 + 3]);
        }
    }
}

extern "C" void kernel_launch(void* const* d_in, const int* in_sizes, int n_in,
                              void* d_out, int out_size, void* d_ws, size_t ws_size,
                              hipStream_t stream) {
    const float* x    = (const float*)d_in[0];
    const float* sup  = (const float*)d_in[1];
    const float* W    = (const float*)d_in[2];
    const float* bias = (const float*)d_in[3];
    float* out = (float*)d_out;

    __hip_bfloat16* xTb  = (__hip_bfloat16*)d_ws;
    __hip_bfloat16* stpb = xTb + XTB_ELEMS;
    __hip_bfloat16* Wb   = stpb + STP_ELEMS;

    build_stp<<<(int)((STP_ELEMS + 255) / 256), 256, 0, stream>>>(sup, stpb);
    build_wb<<<(int)((WB_ELEMS + 255) / 256), 256, 0, stream>>>(W, Wb);
    transpose_x<<<Bb * NKS, 256, 0, stream>>>(x, xTb);
    graphconv_main<<<Bb * NWT * 2, 768, 0, stream>>>(xTb, stpb, Wb, bias, out);
}

// Round 14
// 297.931 us; speedup vs baseline: 1.7042x; 1.4699x over previous
//
#include <hip/hip_runtime.h>
#include <hip/hip_bf16.h>

typedef short bf16x8 __attribute__((ext_vector_type(8)));
typedef short bf16x4 __attribute__((ext_vector_type(4)));
typedef float f32x4  __attribute__((ext_vector_type(4)));

static constexpr int Bb   = 128;
static constexpr int Cin  = 32;
static constexpr int Nn   = 325;
static constexpr int Tt   = 24;
static constexpr int Cout = 64;
static constexpr int NKS  = 11;    // K steps of 32 (352)
static constexpr int WP   = 336;   // padded w rows per (e,ks) plane
static constexpr int NWT  = 21;    // w-tiles of 16
static constexpr size_t XTB_ELEMS = (size_t)Bb * NKS * (Tt * Cin) * 32;
static constexpr size_t STP_ELEMS = (size_t)4 * NKS * WP * 32;
static constexpr size_t WB_ELEMS  = (size_t)Cout * 128;

__device__ __forceinline__ void gld16(const void* g, void* l) {
    __builtin_amdgcn_global_load_lds(
        (const __attribute__((address_space(1))) void*)g,
        (__attribute__((address_space(3))) void*)l, 16, 0, 0);
}
__device__ __forceinline__ short bfb(float f) {
    __hip_bfloat16 h = __float2bfloat16(f);
    return *reinterpret_cast<short*>(&h);
}

// ---------- P1: stpb[e][ks][w(336)][vi(32)], e==0 identity-augmented ------
__global__ void build_stp(const float* __restrict__ sup,
                          __hip_bfloat16* __restrict__ stpb) {
    int idx = blockIdx.x * 256 + threadIdx.x;
    int total = 4 * NKS * WP * 32;
    if (idx >= total) return;
    int e  = idx / (NKS * WP * 32);
    int r  = idx % (NKS * WP * 32);
    int ks = r / (WP * 32);
    int r2 = r % (WP * 32);
    int w  = r2 / 32;
    int vi = r2 % 32;
    int v  = ks * 32 + vi;
    float val = 0.f;
    if (e == 0) {
        val = (v == w && v < Nn) ? 1.f : 0.f;
    } else if (v < Nn && w < Nn) {
        val = sup[((size_t)(e - 1) * Nn + v) * Nn + w];
    }
    stpb[idx] = __float2bfloat16(val);
}

// ---------- P1b: W fp32 -> bf16 [64][128] ---------------------------------
__global__ void build_wb(const float* __restrict__ W,
                         __hip_bfloat16* __restrict__ Wb) {
    int i = blockIdx.x * 256 + threadIdx.x;
    if (i < Cout * 128) Wb[i] = __float2bfloat16(W[i]);
}

// ---------- P2: x -> xTb[b][ks][ct=t*32+c][vi(32)]; XCD-affine: b/16 ------
__global__ void transpose_x(const float* __restrict__ x,
                            __hip_bfloat16* __restrict__ xTb) {
    __shared__ __hip_bfloat16 ls[Cin * 32 * 28];   // [c][vi][28]
    int xcd = blockIdx.x & 7;
    int idx = blockIdx.x >> 3;        // [0,176): 16 b x 11 ks
    int b   = xcd * 16 + idx / NKS;
    int ks  = idx % NKS;
    int tid = threadIdx.x;
    for (int i = 0; i < 24; ++i) {
        int f4 = i * 256 + tid;
        int c  = f4 / 192;
        int rm = f4 % 192;
        int vi = rm / 6;
        int t0 = (rm % 6) * 4;
        int v  = ks * 32 + vi;
        float4 val = make_float4(0.f, 0.f, 0.f, 0.f);
        if (v < Nn)
            val = *(const float4*)(x + (((size_t)(b * Cin + c) * Nn + v) * Tt + t0));
        bf16x4 pk = { bfb(val.x), bfb(val.y), bfb(val.z), bfb(val.w) };
        *(bf16x4*)&ls[(c * 32 + vi) * 28 + t0] = pk;
    }
    __syncthreads();
    for (int j = 0; j < 12; ++j) {
        int o    = j * 256 + tid;
        int row  = o >> 2;
        int slot = o & 3;
        int t = row >> 5, c = row & 31;
        union { short us[8]; bf16x8 v8; } pk;
#pragma unroll
        for (int q = 0; q < 8; ++q) {
            __hip_bfloat16 h = ls[(c * 32 + slot * 8 + q) * 28 + t];
            pk.us[q] = *reinterpret_cast<short*>(&h);
        }
        *(bf16x8*)((char*)xTb + ((size_t)(b * NKS + ks) * 768 + row) * 64 + slot * 16) = pk.v8;
    }
}

// ---------- M: block=(b,wt) 512thr/8waves; wave-private LDS X-ring --------
// K-loop: zero barriers, counted vmcnt(6), gld16 staging (no VGPR cost).
__global__ __launch_bounds__(512, 1) void graphconv_main(
    const __hip_bfloat16* __restrict__ xTb,
    const __hip_bfloat16* __restrict__ stpb,
    const __hip_bfloat16* __restrict__ Wb,
    const float* __restrict__ bias,
    float* __restrict__ out) {
    // ring: 2 halves x 8 waves x 6 KB = 98304 B; Ss: 44 KB. Os overlays ring.
    __shared__ alignas(16) char smem[98304 + 45056];
    char*  ring = smem;
    char*  Ss   = smem + 98304;
    float* Os   = (float*)smem;    // 32 o x (16 w x 25) = 51200 B

    // bijective XCD swizzle: 2688 = 8 * 336; wt innermost (X L2 reuse x21)
    int bid = blockIdx.x;
    int lg  = (bid & 7) * 336 + (bid >> 3);
    int b   = lg / NWT;
    int wt  = lg % NWT;
    int w0  = wt * 16;

    int tid = threadIdx.x, wid = tid >> 6, lane = tid & 63;
    int cl = lane & 15, kg = lane >> 4;

    int srow  = lane >> 2;                             // row 0..15
    int sslot = ((lane & 3) ^ ((lane >> 3) & 3)) << 4; // R5-verified pair
    const int asw = (kg ^ ((cl >> 1) & 3)) << 4;

    const char* xslab = (const char*)xTb + (size_t)b * NKS * 768 * 64;
    const char* xsrc  = xslab + (size_t)(wid * 96 + srow) * 64 + sslot;
    char*       xdst  = ring + wid * 6144 + lane * 16;

    // ---- prologue: S' (5-6 gld16/wave), then X ring ks=0,1 (12 gld16) ----
    for (int i = wid; i < 44; i += 8) {
        gld16((const char*)stpb + ((size_t)i * WP + w0 + srow) * 64 + sslot,
              Ss + i * 1024 + lane * 16);
    }
#pragma unroll
    for (int s = 0; s < 2; ++s)
#pragma unroll
        for (int q = 0; q < 6; ++q)
            gld16(xsrc + (size_t)s * 49152 + q * 1024,
                  xdst + s * 49152 + q * 1024);

    asm volatile("s_waitcnt vmcnt(12)" ::: "memory");   // S' arrived (own)
    __builtin_amdgcn_sched_barrier(0);
    __builtin_amdgcn_s_barrier();                       // S' visible, no drain

    // ---- GEMM1 K-loop: barrier-free, counted vmcnt ----
    f32x4 acc1[4][6] = {};
#pragma unroll
    for (int ks = 0; ks < NKS; ++ks) {
        if (ks < 10) { asm volatile("s_waitcnt vmcnt(6)" ::: "memory"); }
        else         { asm volatile("s_waitcnt vmcnt(0)" ::: "memory"); }
        __builtin_amdgcn_sched_barrier(0);
        const int bsel = (ks & 1) * 49152;
        bf16x8 xf[6], af[4];
#pragma unroll
        for (int j = 0; j < 6; ++j)
            xf[j] = *(const bf16x8*)(ring + bsel + wid * 6144 + j * 1024 +
                                     cl * 64 + asw);
#pragma unroll
        for (int e = 0; e < 4; ++e)
            af[e] = *(const bf16x8*)(Ss + (e * NKS + ks) * 1024 + cl * 64 + asw);
        __builtin_amdgcn_s_setprio(1);
#pragma unroll
        for (int e = 0; e < 4; ++e)
#pragma unroll
            for (int j = 0; j < 6; ++j)
                acc1[e][j] = __builtin_amdgcn_mfma_f32_16x16x32_bf16(
                    xf[j], af[e], acc1[e][j], 0, 0, 0);
        __builtin_amdgcn_s_setprio(0);
        if (ks < 9) {   // restage own region for ks+2 (reads above complete)
            asm volatile("s_waitcnt lgkmcnt(0)" ::: "memory");
            __builtin_amdgcn_sched_barrier(0);
#pragma unroll
            for (int q = 0; q < 6; ++q)
                gld16(xsrc + (size_t)(ks + 2) * 49152 + q * 1024,
                      xdst + bsel + q * 1024);
        }
    }

    // ---- GEMM2 from registers: kappa = es*2 + (j&1), tj = j>>1 ----
    // lane holds Y^T[ct = wid*96 + j*16 + kg*4 + r][w = w0+cl], t = wid*3+tj
    f32x4 acc2[4][3] = {};
#pragma unroll
    for (int kappa = 0; kappa < 8; ++kappa) {
        const int es = kappa >> 1, half = kappa & 1;
        bf16x4 wf[4];
#pragma unroll
        for (int mt = 0; mt < 4; ++mt)
            wf[mt] = *(const bf16x4*)((const char*)Wb + (mt * 16 + cl) * 256 +
                                      kappa * 32 + kg * 8);
#pragma unroll
        for (int tj = 0; tj < 3; ++tj) {
            const int j = tj * 2 + half;
            f32x4 y = acc1[es][j];
            bf16x4 pb = { bfb(y[0]), bfb(y[1]), bfb(y[2]), bfb(y[3]) };
#pragma unroll
            for (int mt = 0; mt < 4; ++mt)
                acc2[mt][tj] = __builtin_amdgcn_mfma_f32_16x16x16bf16_1k(
                    wf[mt], pb, acc2[mt][tj], 0, 0, 0);
        }
    }

    // ---- epilogue: Os overlays ring; 2 passes of 32 o; full 96B rows ----
    asm volatile("s_waitcnt vmcnt(0) lgkmcnt(0)" ::: "memory");
    __builtin_amdgcn_s_barrier();          // all ring/Ss reads done
#pragma unroll
    for (int p = 0; p < 2; ++p) {
        if (p) {
            asm volatile("s_waitcnt lgkmcnt(0)" ::: "memory");
            __builtin_amdgcn_s_barrier();  // pass-0 reads done
        }
#pragma unroll
        for (int mh = 0; mh < 2; ++mh) {
            const int mt = p * 2 + mh;
#pragma unroll
            for (int tj = 0; tj < 3; ++tj) {
                const int t = wid * 3 + tj;
#pragma unroll
                for (int r2_ = 0; r2_ < 4; ++r2_)
                    Os[(mh * 16 + kg * 4 + r2_) * 400 + cl * 25 + t] =
                        acc2[mt][tj][r2_];
            }
        }
        asm volatile("s_waitcnt lgkmcnt(0)" ::: "memory");
        __builtin_amdgcn_s_barrier();
        const int o2 = tid >> 4, w = tid & 15;   // 512 threads = 32 o x 16 w
        const int wg = w0 + w;
        if (wg < Nn) {
            const int o = p * 32 + o2;
            const float bv = bias[o];
            float f[24];
#pragma unroll
            for (int t = 0; t < 24; ++t)
                f[t] = Os[o2 * 400 + w * 25 + t] + bv;
            float* op = out + ((size_t)(b * Cout + o) * Nn + wg) * Tt;
#pragma unroll
            for (int q3 = 0; q3 < 6; ++q3)
                *(float4*)(op + q3 * 4) = make_float4(
                    f[q3 * 4], f[q3 * 4 + 1], f[q3 * 4 + 2], f[q3 * 4 + 3]);
        }
    }
}

extern "C" void kernel_launch(void* const* d_in, const int* in_sizes, int n_in,
                              void* d_out, int out_size, void* d_ws, size_t ws_size,
                              hipStream_t stream) {
    const float* x    = (const float*)d_in[0];
    const float* sup  = (const float*)d_in[1];
    const float* W    = (const float*)d_in[2];
    const float* bias = (const float*)d_in[3];
    float* out = (float*)d_out;

    __hip_bfloat16* xTb  = (__hip_bfloat16*)d_ws;
    __hip_bfloat16* stpb = xTb + XTB_ELEMS;
    __hip_bfloat16* Wb   = stpb + STP_ELEMS;

    build_stp<<<(int)((STP_ELEMS + 255) / 256), 256, 0, stream>>>(sup, stpb);
    build_wb<<<(int)((WB_ELEMS + 255) / 256), 256, 0, stream>>>(W, Wb);
    transpose_x<<<Bb * NKS, 256, 0, stream>>>(x, xTb);
    graphconv_main<<<Bb * NWT, 512, 0, stream>>>(xTb, stpb, Wb, bias, out);
}

// Round 15
// 295.892 us; speedup vs baseline: 1.7159x; 1.0069x over previous
//
#include <hip/hip_runtime.h>
#include <hip/hip_bf16.h>

typedef short bf16x8 __attribute__((ext_vector_type(8)));
typedef short bf16x4 __attribute__((ext_vector_type(4)));
typedef float f32x4  __attribute__((ext_vector_type(4)));

static constexpr int Bb   = 128;
static constexpr int Cin  = 32;
static constexpr int Nn   = 325;
static constexpr int Tt   = 24;
static constexpr int Cout = 64;
static constexpr int NKS  = 11;    // K steps of 32 (352)
static constexpr int WP   = 336;   // padded w rows per (e,ks) plane
static constexpr int NWT  = 21;    // w-tiles of 16
static constexpr size_t XTB_ELEMS = (size_t)Bb * NKS * (Tt * Cin) * 32;
static constexpr size_t STP_ELEMS = (size_t)4 * NKS * WP * 32;
static constexpr size_t WB_ELEMS  = (size_t)Cout * 128;

__device__ __forceinline__ void gld16(const void* g, void* l) {
    __builtin_amdgcn_global_load_lds(
        (const __attribute__((address_space(1))) void*)g,
        (__attribute__((address_space(3))) void*)l, 16, 0, 0);
}
__device__ __forceinline__ short bfb(float f) {
    __hip_bfloat16 h = __float2bfloat16(f);
    return *reinterpret_cast<short*>(&h);
}

// ---------- P1: fused stpb + Wb build ------------------------------------
// stpb[e][ks][w(336)][vi(32)], e==0 identity; then Wb = bf16(W).
__global__ void build_tabs(const float* __restrict__ sup,
                           const float* __restrict__ W,
                           __hip_bfloat16* __restrict__ stpb,
                           __hip_bfloat16* __restrict__ Wb) {
    int idx = blockIdx.x * 256 + threadIdx.x;
    int total = 4 * NKS * WP * 32;
    if (idx < total) {
        int e  = idx / (NKS * WP * 32);
        int r  = idx % (NKS * WP * 32);
        int ks = r / (WP * 32);
        int r2 = r % (WP * 32);
        int w  = r2 / 32;
        int vi = r2 % 32;
        int v  = ks * 32 + vi;
        float val = 0.f;
        if (e == 0) {
            val = (v == w && v < Nn) ? 1.f : 0.f;
        } else if (v < Nn && w < Nn) {
            val = sup[((size_t)(e - 1) * Nn + v) * Nn + w];
        }
        stpb[idx] = __float2bfloat16(val);
    } else {
        int wi = idx - total;
        if (wi < Cout * 128) Wb[wi] = __float2bfloat16(W[wi]);
    }
}

// ---------- P2: x -> xTb[b][ks][ct=t*32+c][vi(32)]; XCD-affine: b/16 ------
__global__ void transpose_x(const float* __restrict__ x,
                            __hip_bfloat16* __restrict__ xTb) {
    __shared__ __hip_bfloat16 ls[Cin * 32 * 28];   // [c][vi][28]
    int xcd = blockIdx.x & 7;
    int idx = blockIdx.x >> 3;        // [0,176): 16 b x 11 ks
    int b   = xcd * 16 + idx / NKS;
    int ks  = idx % NKS;
    int tid = threadIdx.x;
    for (int i = 0; i < 24; ++i) {
        int f4 = i * 256 + tid;
        int c  = f4 / 192;
        int rm = f4 % 192;
        int vi = rm / 6;
        int t0 = (rm % 6) * 4;
        int v  = ks * 32 + vi;
        float4 val = make_float4(0.f, 0.f, 0.f, 0.f);
        if (v < Nn)
            val = *(const float4*)(x + (((size_t)(b * Cin + c) * Nn + v) * Tt + t0));
        bf16x4 pk = { bfb(val.x), bfb(val.y), bfb(val.z), bfb(val.w) };
        *(bf16x4*)&ls[(c * 32 + vi) * 28 + t0] = pk;
    }
    __syncthreads();
    for (int j = 0; j < 12; ++j) {
        int o    = j * 256 + tid;
        int row  = o >> 2;
        int slot = o & 3;
        int t = row >> 5, c = row & 31;
        union { short us[8]; bf16x8 v8; } pk;
#pragma unroll
        for (int q = 0; q < 8; ++q) {
            __hip_bfloat16 h = ls[(c * 32 + slot * 8 + q) * 28 + t];
            pk.us[q] = *reinterpret_cast<short*>(&h);
        }
        *(bf16x8*)((char*)xTb + ((size_t)(b * NKS + ks) * 768 + row) * 64 + slot * 16) = pk.v8;
    }
}

// ---------- M: block=(b,wt) 512thr/8waves; wave-private LDS X-ring --------
// K-loop: zero barriers, counted vmcnt(6); restage BEFORE the MFMA batch.
__global__ __launch_bounds__(512, 1) void graphconv_main(
    const __hip_bfloat16* __restrict__ xTb,
    const __hip_bfloat16* __restrict__ stpb,
    const __hip_bfloat16* __restrict__ Wb,
    const float* __restrict__ bias,
    float* __restrict__ out) {
    // ring: 2 halves x 8 waves x 6 KB = 98304 B; Ss: 44 KB. Os overlays ring.
    __shared__ alignas(16) char smem[98304 + 45056];
    char*  ring = smem;
    char*  Ss   = smem + 98304;
    float* Os   = (float*)smem;    // 32 o x (16 w x 25) = 51200 B

    // bijective XCD swizzle: 2688 = 8 * 336; wt innermost (X L2 reuse x21)
    int bid = blockIdx.x;
    int lg  = (bid & 7) * 336 + (bid >> 3);
    int b   = lg / NWT;
    int wt  = lg % NWT;
    int w0  = wt * 16;

    int tid = threadIdx.x, wid = tid >> 6, lane = tid & 63;
    int cl = lane & 15, kg = lane >> 4;

    int srow  = lane >> 2;                             // row 0..15
    int sslot = ((lane & 3) ^ ((lane >> 3) & 3)) << 4; // R5-verified pair
    const int asw = (kg ^ ((cl >> 1) & 3)) << 4;

    const char* xslab = (const char*)xTb + (size_t)b * NKS * 768 * 64;
    const char* xsrc  = xslab + (size_t)(wid * 96 + srow) * 64 + sslot;
    char*       xdst  = ring + wid * 6144 + lane * 16;

    // ---- prologue: S' (5-6 gld16/wave), then X ring ks=0,1 (12 gld16) ----
    for (int i = wid; i < 44; i += 8) {
        gld16((const char*)stpb + ((size_t)i * WP + w0 + srow) * 64 + sslot,
              Ss + i * 1024 + lane * 16);
    }
#pragma unroll
    for (int s = 0; s < 2; ++s)
#pragma unroll
        for (int q = 0; q < 6; ++q)
            gld16(xsrc + (size_t)s * 49152 + q * 1024,
                  xdst + s * 49152 + q * 1024);

    asm volatile("s_waitcnt vmcnt(12)" ::: "memory");   // S' arrived (own)
    __builtin_amdgcn_sched_barrier(0);
    __builtin_amdgcn_s_barrier();                       // S' visible, no drain

    // ---- GEMM1 K-loop: barrier-free, counted vmcnt, restage-early ----
    f32x4 acc1[4][6] = {};
#pragma unroll
    for (int ks = 0; ks < NKS; ++ks) {
        if (ks < 10) { asm volatile("s_waitcnt vmcnt(6)" ::: "memory"); }
        else         { asm volatile("s_waitcnt vmcnt(0)" ::: "memory"); }
        __builtin_amdgcn_sched_barrier(0);
        const int bsel = (ks & 1) * 49152;
        // xf reads first (pinned before the lgkm fence below)
        bf16x8 xf[6];
#pragma unroll
        for (int j = 0; j < 6; ++j)
            xf[j] = *(const bf16x8*)(ring + bsel + wid * 6144 + j * 1024 +
                                     cl * 64 + asw);
        // fence: xf data in regs; then immediately restage this buffer for
        // ks+2 so the loads get a full MFMA-batch of flight time.
        asm volatile("s_waitcnt lgkmcnt(0)" ::: "memory");
        __builtin_amdgcn_sched_barrier(0);
        if (ks < 9) {
#pragma unroll
            for (int q = 0; q < 6; ++q)
                gld16(xsrc + (size_t)(ks + 2) * 49152 + q * 1024,
                      xdst + bsel + q * 1024);
        }
        // af reads (Ss region, disjoint from ring) overlap MFMA start
        bf16x8 af[4];
#pragma unroll
        for (int e = 0; e < 4; ++e)
            af[e] = *(const bf16x8*)(Ss + (e * NKS + ks) * 1024 + cl * 64 + asw);
#pragma unroll
        for (int e = 0; e < 4; ++e)
#pragma unroll
            for (int j = 0; j < 6; ++j)
                acc1[e][j] = __builtin_amdgcn_mfma_f32_16x16x32_bf16(
                    xf[j], af[e], acc1[e][j], 0, 0, 0);
    }

    // ---- GEMM2 from registers: kappa = es*2 + (j&1), tj = j>>1 ----
    // lane holds Y^T[ct = wid*96 + j*16 + kg*4 + r][w = w0+cl], t = wid*3+tj
    f32x4 acc2[4][3] = {};
#pragma unroll
    for (int kappa = 0; kappa < 8; ++kappa) {
        const int es = kappa >> 1, half = kappa & 1;
        bf16x4 wf[4];
#pragma unroll
        for (int mt = 0; mt < 4; ++mt)
            wf[mt] = *(const bf16x4*)((const char*)Wb + (mt * 16 + cl) * 256 +
                                      kappa * 32 + kg * 8);
#pragma unroll
        for (int tj = 0; tj < 3; ++tj) {
            const int j = tj * 2 + half;
            f32x4 y = acc1[es][j];
            bf16x4 pb = { bfb(y[0]), bfb(y[1]), bfb(y[2]), bfb(y[3]) };
#pragma unroll
            for (int mt = 0; mt < 4; ++mt)
                acc2[mt][tj] = __builtin_amdgcn_mfma_f32_16x16x16bf16_1k(
                    wf[mt], pb, acc2[mt][tj], 0, 0, 0);
        }
    }

    // ---- epilogue: Os overlays ring; 2 passes of 32 o; full 96B rows ----
    __builtin_amdgcn_s_barrier();          // all ring/Ss reads done (per-wave)
#pragma unroll
    for (int p = 0; p < 2; ++p) {
        if (p) {
            asm volatile("s_waitcnt lgkmcnt(0)" ::: "memory");
            __builtin_amdgcn_s_barrier();  // pass-0 reads done
        }
#pragma unroll
        for (int mh = 0; mh < 2; ++mh) {
            const int mt = p * 2 + mh;
#pragma unroll
            for (int tj = 0; tj < 3; ++tj) {
                const int t = wid * 3 + tj;
#pragma unroll
                for (int r2_ = 0; r2_ < 4; ++r2_)
                    Os[(mh * 16 + kg * 4 + r2_) * 400 + cl * 25 + t] =
                        acc2[mt][tj][r2_];
            }
        }
        asm volatile("s_waitcnt lgkmcnt(0)" ::: "memory");
        __builtin_amdgcn_s_barrier();
        const int o2 = tid >> 4, w = tid & 15;   // 512 threads = 32 o x 16 w
        const int wg = w0 + w;
        if (wg < Nn) {
            const int o = p * 32 + o2;
            const float bv = bias[o];
            float f[24];
#pragma unroll
            for (int t = 0; t < 24; ++t)
                f[t] = Os[o2 * 400 + w * 25 + t] + bv;
            float* op = out + ((size_t)(b * Cout + o) * Nn + wg) * Tt;
#pragma unroll
            for (int q3 = 0; q3 < 6; ++q3)
                *(float4*)(op + q3 * 4) = make_float4(
                    f[q3 * 4], f[q3 * 4 + 1], f[q3 * 4 + 2], f[q3 * 4 + 3]);
        }
    }
}

extern "C" void kernel_launch(void* const* d_in, const int* in_sizes, int n_in,
                              void* d_out, int out_size, void* d_ws, size_t ws_size,
                              hipStream_t stream) {
    const float* x    = (const float*)d_in[0];
    const float* sup  = (const float*)d_in[1];
    const float* W    = (const float*)d_in[2];
    const float* bias = (const float*)d_in[3];
    float* out = (float*)d_out;

    __hip_bfloat16* xTb  = (__hip_bfloat16*)d_ws;
    __hip_bfloat16* stpb = xTb + XTB_ELEMS;
    __hip_bfloat16* Wb   = stpb + STP_ELEMS;

    int build_total = (int)(STP_ELEMS + WB_ELEMS);
    build_tabs<<<(build_total + 255) / 256, 256, 0, stream>>>(sup, W, stpb, Wb);
    transpose_x<<<Bb * NKS, 256, 0, stream>>>(x, xTb);
    graphconv_main<<<Bb * NWT, 512, 0, stream>>>(xTb, stpb, Wb, bias, out);
}

// Round 16
// 282.197 us; speedup vs baseline: 1.7992x; 1.0485x over previous
//
#include <hip/hip_runtime.h>
#include <hip/hip_bf16.h>

typedef short bf16x8 __attribute__((ext_vector_type(8)));
typedef short bf16x4 __attribute__((ext_vector_type(4)));
typedef float f32x4  __attribute__((ext_vector_type(4)));

static constexpr int Bb   = 128;
static constexpr int Cin  = 32;
static constexpr int Nn   = 325;
static constexpr int Tt   = 24;
static constexpr int Cout = 64;
static constexpr int NKS  = 11;    // K steps of 32 (352)
static constexpr int WP   = 336;   // padded w rows per (ep,ks) plane
static constexpr int NWT  = 21;    // w-tiles of 16
static constexpr size_t XTB_ELEMS = (size_t)Bb * NKS * (Tt * Cin) * 32;
static constexpr size_t STP_ELEMS = (size_t)3 * NKS * WP * 32;   // no identity
static constexpr size_t WB_ELEMS  = (size_t)Cout * 128;

__device__ __forceinline__ void gld16(const void* g, void* l) {
    __builtin_amdgcn_global_load_lds(
        (const __attribute__((address_space(1))) void*)g,
        (__attribute__((address_space(3))) void*)l, 16, 0, 0);
}
__device__ __forceinline__ short bfb(float f) {
    __hip_bfloat16 h = __float2bfloat16(f);
    return *reinterpret_cast<short*>(&h);
}

// ---------- P1: fused build: stpb[ep][ks][w(336)][vi] (ep=e-1) + Wb -------
__global__ void build_tabs(const float* __restrict__ sup,
                           const float* __restrict__ W,
                           __hip_bfloat16* __restrict__ stpb,
                           __hip_bfloat16* __restrict__ Wb) {
    int idx = blockIdx.x * 256 + threadIdx.x;
    int total = 3 * NKS * WP * 32;
    if (idx < total) {
        int ep = idx / (NKS * WP * 32);
        int r  = idx % (NKS * WP * 32);
        int ks = r / (WP * 32);
        int r2 = r % (WP * 32);
        int w  = r2 / 32;
        int vi = r2 % 32;
        int v  = ks * 32 + vi;
        float val = 0.f;
        if (v < Nn && w < Nn)
            val = sup[((size_t)ep * Nn + v) * Nn + w];
        stpb[idx] = __float2bfloat16(val);
    } else {
        int wi = idx - total;
        if (wi < Cout * 128) Wb[wi] = __float2bfloat16(W[wi]);
    }
}

// ---------- P2: x -> xTb[b][ks][ct=t*32+c][vi(32)]; XCD-affine: b/16 ------
__global__ void transpose_x(const float* __restrict__ x,
                            __hip_bfloat16* __restrict__ xTb) {
    __shared__ __hip_bfloat16 ls[Cin * 32 * 28];   // [c][vi][28]
    int xcd = blockIdx.x & 7;
    int idx = blockIdx.x >> 3;        // [0,176): 16 b x 11 ks
    int b   = xcd * 16 + idx / NKS;
    int ks  = idx % NKS;
    int tid = threadIdx.x;
    for (int i = 0; i < 24; ++i) {
        int f4 = i * 256 + tid;
        int c  = f4 / 192;
        int rm = f4 % 192;
        int vi = rm / 6;
        int t0 = (rm % 6) * 4;
        int v  = ks * 32 + vi;
        float4 val = make_float4(0.f, 0.f, 0.f, 0.f);
        if (v < Nn)
            val = *(const float4*)(x + (((size_t)(b * Cin + c) * Nn + v) * Tt + t0));
        bf16x4 pk = { bfb(val.x), bfb(val.y), bfb(val.z), bfb(val.w) };
        *(bf16x4*)&ls[(c * 32 + vi) * 28 + t0] = pk;
    }
    __syncthreads();
    for (int j = 0; j < 12; ++j) {
        int o    = j * 256 + tid;
        int row  = o >> 2;
        int slot = o & 3;
        int t = row >> 5, c = row & 31;
        union { short us[8]; bf16x8 v8; } pk;
#pragma unroll
        for (int q = 0; q < 8; ++q) {
            __hip_bfloat16 h = ls[(c * 32 + slot * 8 + q) * 28 + t];
            pk.us[q] = *reinterpret_cast<short*>(&h);
        }
        *(bf16x8*)((char*)xTb + ((size_t)(b * NKS + ks) * 768 + row) * 64 + slot * 16) = pk.v8;
    }
}

// ---------- M: block=(b,wt) 512thr/8waves; identity synthesized -----------
// K-loop: zero barriers, counted vmcnt(6); 18 MFMA/iter (3 e-planes) + 6
// identity MFMAs at the single K-step ks == wt>>1 (in-register B-frag).
__global__ __launch_bounds__(512, 1) void graphconv_main(
    const __hip_bfloat16* __restrict__ xTb,
    const __hip_bfloat16* __restrict__ stpb,
    const __hip_bfloat16* __restrict__ Wb,
    const float* __restrict__ bias,
    float* __restrict__ out) {
    // ring: 2 x 8 x 6 KB = 98304 B; Ss: 33 KB. Os overlays ring.
    __shared__ alignas(16) char smem[98304 + 33792];
    char*  ring = smem;
    char*  Ss   = smem + 98304;
    float* Os   = (float*)smem;    // 32 o x (16 w x 25) = 51200 B

    // bijective XCD swizzle: 2688 = 8 * 336; wt innermost (X L2 reuse x21)
    int bid = blockIdx.x;
    int lg  = (bid & 7) * 336 + (bid >> 3);
    int b   = lg / NWT;
    int wt  = lg % NWT;
    int w0  = wt * 16;

    int tid = threadIdx.x, wid = tid >> 6, lane = tid & 63;
    int cl = lane & 15, kg = lane >> 4;

    int srow  = lane >> 2;                             // row 0..15
    int sslot = ((lane & 3) ^ ((lane >> 3) & 3)) << 4; // R5-verified pair
    const int asw = (kg ^ ((cl >> 1) & 3)) << 4;

    const char* xslab = (const char*)xTb + (size_t)b * NKS * 768 * 64;
    const char* xsrc  = xslab + (size_t)(wid * 96 + srow) * 64 + sslot;
    char*       xdst  = ring + wid * 6144 + lane * 16;

    // ---- prologue: S' 33 slabs (<=5 gld16/wave), then X ks=0,1 ----
    for (int i = wid; i < 33; i += 8) {
        gld16((const char*)stpb + ((size_t)i * WP + w0 + srow) * 64 + sslot,
              Ss + i * 1024 + lane * 16);
    }
#pragma unroll
    for (int s = 0; s < 2; ++s)
#pragma unroll
        for (int q = 0; q < 6; ++q)
            gld16(xsrc + (size_t)s * 49152 + q * 1024,
                  xdst + s * 49152 + q * 1024);

    // identity B-frag (R13-verified): hot at ks==wt>>1, k = 16*(wt&1)+cl
    bf16x8 idf;
    {
        short hot = (kg == 2 * (wt & 1) + (cl >> 3)) ? (short)0x3F80 : (short)0;
        bf16x8 z = { 0, 0, 0, 0, 0, 0, 0, 0 };
#pragma unroll
        for (int i = 0; i < 8; ++i)
            z[i] = (i == (cl & 7)) ? hot : (short)0;
        idf = z;
    }
    const int id_ks = wt >> 1;

    asm volatile("s_waitcnt vmcnt(12)" ::: "memory");   // own S' drained
    __builtin_amdgcn_sched_barrier(0);
    __builtin_amdgcn_s_barrier();                       // S' visible, no drain

    // ---- GEMM1 K-loop: barrier-free, counted vmcnt ----
    f32x4 acc1[3][6] = {};
    f32x4 aid[6]     = {};
#pragma unroll
    for (int ks = 0; ks < NKS; ++ks) {
        if (ks < 10) { asm volatile("s_waitcnt vmcnt(6)" ::: "memory"); }
        else         { asm volatile("s_waitcnt vmcnt(0)" ::: "memory"); }
        __builtin_amdgcn_sched_barrier(0);
        const int bsel = (ks & 1) * 49152;
        bf16x8 xf[6];
#pragma unroll
        for (int j = 0; j < 6; ++j)
            xf[j] = *(const bf16x8*)(ring + bsel + wid * 6144 + j * 1024 +
                                     cl * 64 + asw);
        asm volatile("s_waitcnt lgkmcnt(0)" ::: "memory");
        __builtin_amdgcn_sched_barrier(0);
        if (ks < 9) {   // restage this buffer for ks+2 (xf in regs)
#pragma unroll
            for (int q = 0; q < 6; ++q)
                gld16(xsrc + (size_t)(ks + 2) * 49152 + q * 1024,
                      xdst + bsel + q * 1024);
        }
        bf16x8 af[3];
#pragma unroll
        for (int ep = 0; ep < 3; ++ep)
            af[ep] = *(const bf16x8*)(Ss + (ep * NKS + ks) * 1024 + cl * 64 + asw);
#pragma unroll
        for (int ep = 0; ep < 3; ++ep)
#pragma unroll
            for (int j = 0; j < 6; ++j)
                acc1[ep][j] = __builtin_amdgcn_mfma_f32_16x16x32_bf16(
                    xf[j], af[ep], acc1[ep][j], 0, 0, 0);
        if (ks == id_ks) {   // block-uniform branch; 6 MFMAs once per block
#pragma unroll
            for (int j = 0; j < 6; ++j)
                aid[j] = __builtin_amdgcn_mfma_f32_16x16x32_bf16(
                    xf[j], idf, aid[j], 0, 0, 0);
        }
    }

    // ---- GEMM2 from registers: kappa = es*2 + (j&1), tj = j>>1 ----
    // es==0 -> identity slice (aid), else acc1[es-1].
    f32x4 acc2[4][3] = {};
#pragma unroll
    for (int kappa = 0; kappa < 8; ++kappa) {
        const int es = kappa >> 1, half = kappa & 1;
        bf16x4 wf[4];
#pragma unroll
        for (int mt = 0; mt < 4; ++mt)
            wf[mt] = *(const bf16x4*)((const char*)Wb + (mt * 16 + cl) * 256 +
                                      kappa * 32 + kg * 8);
#pragma unroll
        for (int tj = 0; tj < 3; ++tj) {
            const int j = tj * 2 + half;
            f32x4 y = (es == 0) ? aid[j] : acc1[es - 1][j];
            bf16x4 pb = { bfb(y[0]), bfb(y[1]), bfb(y[2]), bfb(y[3]) };
#pragma unroll
            for (int mt = 0; mt < 4; ++mt)
                acc2[mt][tj] = __builtin_amdgcn_mfma_f32_16x16x16bf16_1k(
                    wf[mt], pb, acc2[mt][tj], 0, 0, 0);
        }
    }

    // ---- epilogue: Os overlays ring; 2 passes of 32 o; full 96B rows ----
    __builtin_amdgcn_s_barrier();          // all ring/Ss reads done
#pragma unroll
    for (int p = 0; p < 2; ++p) {
        if (p) {
            asm volatile("s_waitcnt lgkmcnt(0)" ::: "memory");
            __builtin_amdgcn_s_barrier();  // pass-0 reads done
        }
#pragma unroll
        for (int mh = 0; mh < 2; ++mh) {
            const int mt = p * 2 + mh;
#pragma unroll
            for (int tj = 0; tj < 3; ++tj) {
                const int t = wid * 3 + tj;
#pragma unroll
                for (int r2_ = 0; r2_ < 4; ++r2_)
                    Os[(mh * 16 + kg * 4 + r2_) * 400 + cl * 25 + t] =
                        acc2[mt][tj][r2_];
            }
        }
        asm volatile("s_waitcnt lgkmcnt(0)" ::: "memory");
        __builtin_amdgcn_s_barrier();
        const int o2 = tid >> 4, w = tid & 15;   // 512 threads = 32 o x 16 w
        const int wg = w0 + w;
        if (wg < Nn) {
            const int o = p * 32 + o2;
            const float bv = bias[o];
            float f[24];
#pragma unroll
            for (int t = 0; t < 24; ++t)
                f[t] = Os[o2 * 400 + w * 25 + t] + bv;
            float* op = out + ((size_t)(b * Cout + o) * Nn + wg) * Tt;
#pragma unroll
            for (int q3 = 0; q3 < 6; ++q3)
                *(float4*)(op + q3 * 4) = make_float4(
                    f[q3 * 4], f[q3 * 4 + 1], f[q3 * 4 + 2], f[q3 * 4 + 3]);
        }
    }
}

extern "C" void kernel_launch(void* const* d_in, const int* in_sizes, int n_in,
                              void* d_out, int out_size, void* d_ws, size_t ws_size,
                              hipStream_t stream) {
    const float* x    = (const float*)d_in[0];
    const float* sup  = (const float*)d_in[1];
    const float* W    = (const float*)d_in[2];
    const float* bias = (const float*)d_in[3];
    float* out = (float*)d_out;

    __hip_bfloat16* xTb  = (__hip_bfloat16*)d_ws;
    __hip_bfloat16* stpb = xTb + XTB_ELEMS;
    __hip_bfloat16* Wb   = stpb + STP_ELEMS;

    int build_total = (int)(STP_ELEMS + WB_ELEMS);
    build_tabs<<<(build_total + 255) / 256, 256, 0, stream>>>(sup, W, stpb, Wb);
    transpose_x<<<Bb * NKS, 256, 0, stream>>>(x, xTb);
    graphconv_main<<<Bb * NWT, 512, 0, stream>>>(xTb, stpb, Wb, bias, out);
}